// Round 4
// baseline (842.949 us; speedup 1.0000x reference)
//
#include <hip/hip_runtime.h>
#include <cstdint>
#include <cstddef>

typedef __attribute__((ext_vector_type(8))) short short8;
typedef __attribute__((ext_vector_type(4))) short short4v;
typedef __attribute__((ext_vector_type(4))) float float4v;
typedef __attribute__((ext_vector_type(4))) int int4v;
typedef unsigned short ushort_t;

__device__ __forceinline__ ushort_t f2bf(float f) {
  unsigned u = __builtin_bit_cast(unsigned, f);
  u = (u + 0x7FFFu + ((u >> 16) & 1u)) >> 16;  // RNE
  return (ushort_t)u;
}
__device__ __forceinline__ float bf2f(ushort_t h) {
  unsigned u = ((unsigned)h) << 16;
  return __builtin_bit_cast(float, u);
}

__device__ __forceinline__ void gld_lds16(const void* g, void* l) {
  __builtin_amdgcn_global_load_lds(
      (const __attribute__((address_space(1))) void*)g,
      (__attribute__((address_space(3))) void*)l, 16, 0, 0);
}

#define NSLICE 16  // uniform split-K: 128 k-tiles = 16 slices x 8

// ---------------------------------------------------------------------------
// Tiled layout: 64x64 bf16 subtiles, row-major within, subtile (i,j) of a
// [R][C] matrix at elem offset (i*(C/64)+j)*4096.
// ---------------------------------------------------------------------------

// TN GEMM, plain-store split-K: P[z][m][n] = sum_{k in slice z} A[m][k]*B[n][k]
// A:[M][K], B:[N][K] bf16; ATILED/BTILED select row-major vs subtiled source.
// Tile 128x128, BK=64. grid (M/128, N/128, 16), block 256 (4 waves 2x2).
// (256,4): 4 blocks/CU resident (grid = 1024 = 4*256) -> +33% TLP to hide
// the per-k-tile vmcnt(0)+barrier drain; 32-bit offsets keep VGPR <= 128.
__global__ __launch_bounds__(256, 4) void gemm_tn(
    const ushort_t* __restrict__ A, const ushort_t* __restrict__ B,
    float* __restrict__ P, int M, int N, int K, int ATILED, int BTILED) {
  __shared__ ushort_t As[128 * 64];
  __shared__ ushort_t Bs[128 * 64];
  const int tid = threadIdx.x;
  const int lane = tid & 63;
  const int wave = tid >> 6;
  const int wm = (wave & 1) * 64;
  const int wn = (wave >> 1) * 64;
  const int m0 = blockIdx.x * 128;
  const int n0 = blockIdx.y * 128;
  const int t0 = blockIdx.z * 8;
  float* __restrict__ Pc = P + (size_t)blockIdx.z * M * N;

  // 32-bit byte offsets from SGPR bases (max matrix 128 MiB < 4 GiB)
  unsigned aOff[4], bOff[4];
#pragma unroll
  for (int i = 0; i < 4; i++) {
    const int f = i * 4096 + tid * 16;  // flat byte in 16KB LDS tile
    aOff[i] = ATILED
        ? ((unsigned)((m0 >> 6) + (f >> 13)) * (unsigned)(K >> 6)) * 8192u +
              (unsigned)(f & 8191)
        : (unsigned)(m0 + (f >> 7)) * (unsigned)K * 2u + (unsigned)(f & 127);
    bOff[i] = BTILED
        ? ((unsigned)((n0 >> 6) + (f >> 13)) * (unsigned)(K >> 6)) * 8192u +
              (unsigned)(f & 8191)
        : (unsigned)(n0 + (f >> 7)) * (unsigned)K * 2u + (unsigned)(f & 127);
  }
  const unsigned aStep = ATILED ? 8192u : 128u;
  const unsigned bStep = BTILED ? 8192u : 128u;

  float4v acc[4][4] = {};

  for (int t = t0; t < t0 + 8; t++) {
#pragma unroll
    for (int i = 0; i < 4; i++) {
      const int f = i * 4096 + tid * 16;
      gld_lds16((const char*)A + (size_t)(aOff[i] + (unsigned)t * aStep),
                (char*)As + f);
      gld_lds16((const char*)B + (size_t)(bOff[i] + (unsigned)t * bStep),
                (char*)Bs + f);
    }
    __syncthreads();
#pragma unroll
    for (int ks = 0; ks < 64; ks += 32) {
      short8 af[4], bfr[4];
      const int kr = ks + (lane >> 4) * 8;
      const int l15 = lane & 15;
#pragma unroll
      for (int im = 0; im < 4; im++)
        af[im] = *(const short8*)&As[(wm + im * 16 + l15) * 64 + kr];
#pragma unroll
      for (int in = 0; in < 4; in++)
        bfr[in] = *(const short8*)&Bs[(wn + in * 16 + l15) * 64 + kr];
#pragma unroll
      for (int im = 0; im < 4; im++)
#pragma unroll
        for (int in = 0; in < 4; in++)
          acc[im][in] = __builtin_amdgcn_mfma_f32_16x16x32_bf16(
              af[im], bfr[in], acc[im][in], 0, 0, 0);
    }
    __syncthreads();
  }
  // C/D layout: col(n) = lane&15, row(m) = (lane>>4)*4 + reg  [m89/m91]
  const int cn = lane & 15;
  const int cr = (lane >> 4) * 4;
#pragma unroll
  for (int im = 0; im < 4; im++)
#pragma unroll
    for (int in = 0; in < 4; in++)
#pragma unroll
      for (int r = 0; r < 4; r++) {
        int m = wm + im * 16 + cr + r;
        int n = wn + in * 16 + cn;
        Pc[(size_t)(m0 + m) * N + (n0 + n)] = acc[im][in][r];
      }
}

// ---------------------------------------------------------------------------
// NN GEMM: P[z][m][n] = sum_{k in slice z} A[m][k]*B[k][n].
// A:[M][K] row-major; B SUBTILED (per k-step = 16 KiB contiguous). LDS
// granule layout [4k][16n] k4-major; fragments via ds_read_b64_tr_b16
// (addr bits [6:3] select granule column -> +l15*8 bytes) — verified R1.
// ---------------------------------------------------------------------------
__global__ __launch_bounds__(256, 4) void gemm_nn(
    const ushort_t* __restrict__ A, const ushort_t* __restrict__ B,
    float* __restrict__ P, int M, int N, int K) {
  __shared__ ushort_t As[128 * 64];
  __shared__ ushort_t Bs[64 * 128];
  const int tid = threadIdx.x;
  const int lane = tid & 63;
  const int wave = tid >> 6;
  const int wm = (wave & 1) * 64;
  const int wn = (wave >> 1) * 64;
  const int m0 = blockIdx.x * 128;
  const int n0 = blockIdx.y * 128;
  const int t0 = blockIdx.z * 8;
  float* __restrict__ Pc = P + (size_t)blockIdx.z * M * N;

  unsigned aOff[4], bOff[4];
#pragma unroll
  for (int i = 0; i < 4; i++) {
    const int c = i * 256 + tid;
    const int f = i * 4096 + tid * 16;
    const int brow = ((c >> 6) << 2) | ((c >> 1) & 3);        // k in 0..63
    const int bcol = (((c >> 3) & 7) << 4) | ((c & 1) << 3);  // n in 0..127
    bOff[i] = ((unsigned)(n0 >> 6) << 13) +
              (unsigned)((bcol & 64 ? 8192 : 0) + brow * 128 + (bcol & 63) * 2);
    aOff[i] = (unsigned)(m0 + (f >> 7)) * (unsigned)K * 2u + (unsigned)(f & 127);
  }
  const unsigned bStep = (unsigned)(N >> 6) << 13;  // next k-tile subtile row

  const int l15 = lane & 15;
  const int hi = lane >> 4;
  const unsigned BsB =
      (unsigned)(uintptr_t)(__attribute__((address_space(3))) void*)Bs;
  const unsigned trb = BsB + (unsigned)(hi * 2048) + (unsigned)(l15 * 8);

  float4v acc[4][4] = {};

  for (int t = t0; t < t0 + 8; t++) {
#pragma unroll
    for (int i = 0; i < 4; i++) {
      const int f = i * 4096 + tid * 16;
      gld_lds16((const char*)A + (size_t)(aOff[i] + (unsigned)t * 128u),
                (char*)As + f);
      gld_lds16((const char*)B + (size_t)(bOff[i] + (unsigned)t * bStep),
                (char*)Bs + f);
    }
    __syncthreads();
#pragma unroll
    for (int ks = 0; ks < 64; ks += 32) {
      short8 af[4];
      const int kr = ks + hi * 8;
#pragma unroll
      for (int im = 0; im < 4; im++)
        af[im] = *(const short8*)&As[(wm + im * 16 + l15) * 64 + kr];
      short4v r0[4], r1[4];
      const unsigned tb = trb + (unsigned)((ks >> 2) * 1024) + (unsigned)(wn * 8);
#pragma unroll
      for (int in = 0; in < 4; in++) {
        asm volatile(
            "ds_read_b64_tr_b16 %0, %2\n\t"
            "ds_read_b64_tr_b16 %1, %2 offset:1024"
            : "=&v"(r0[in]), "=&v"(r1[in])
            : "v"(tb + (unsigned)(in * 128)));
      }
      asm volatile("s_waitcnt lgkmcnt(0)" ::: "memory");
      __builtin_amdgcn_sched_barrier(0);
#pragma unroll
      for (int im = 0; im < 4; im++)
#pragma unroll
        for (int in = 0; in < 4; in++) {
          short8 bf8 = __builtin_shufflevector(r0[in], r1[in],
                                               0, 1, 2, 3, 4, 5, 6, 7);
          acc[im][in] = __builtin_amdgcn_mfma_f32_16x16x32_bf16(
              af[im], bf8, acc[im][in], 0, 0, 0);
        }
    }
    __syncthreads();
  }
  const int cn = lane & 15;
  const int cr = (lane >> 4) * 4;
#pragma unroll
  for (int im = 0; im < 4; im++)
#pragma unroll
    for (int in = 0; in < 4; in++)
#pragma unroll
      for (int r = 0; r < 4; r++) {
        int m = wm + im * 16 + cr + r;
        int n = wn + in * 16 + cn;
        Pc[(size_t)(m0 + m) * N + (n0 + n)] = acc[im][in][r];
      }
}

// ---------------------------------------------------------------------------
// fp32 [8192][8192] -> bf16 subtiled (fused cast+repack).
// ---------------------------------------------------------------------------
__global__ __launch_bounds__(256) void repack_T_k(
    const float* __restrict__ src, ushort_t* __restrict__ dst) {
  __shared__ ushort_t tile[32][520];
  const int bx = blockIdx.x;  // 16 strips of 512 cols
  const int by = blockIdx.y;  // 256 strips of 32 rows
  const int t = threadIdx.x;
  const int r = t >> 3, cs = (t & 7) * 64;
  const float* s = src + (size_t)(by * 32 + r) * 8192 + bx * 512 + cs;
#pragma unroll
  for (int j = 0; j < 64; j += 4) {
    float4v v = *(const float4v*)(s + j);
    short4v o;
    o.x = (short)f2bf(v.x); o.y = (short)f2bf(v.y);
    o.z = (short)f2bf(v.z); o.w = (short)f2bf(v.w);
    *(short4v*)&tile[r][cs + j] = o;
  }
  __syncthreads();
  const int q = t & 7;
  ushort_t* d = dst + ((size_t)(by >> 1) * 128 + bx * 8) * 4096 +
                (size_t)(by & 1) * 2048 + r * 64 + q * 8;
#pragma unroll
  for (int jj = 0; jj < 8; jj++)
    *(short8*)(d + (size_t)jj * 4096) = *(const short8*)&tile[r][jj * 64 + q * 8];
}

// ---------------------------------------------------------------------------
// fp32 [R][C] -> bf16 transposed [C][R] (x0 only; small).
// ---------------------------------------------------------------------------
__global__ __launch_bounds__(256) void dualcast_f32_k(
    const float* __restrict__ src, ushort_t* __restrict__ dstN,
    ushort_t* __restrict__ dstT, int R, int C) {
  __shared__ float tile[64][65];
  const int c0 = blockIdx.x * 64, r0 = blockIdx.y * 64;
  const int tr = threadIdx.x >> 2, cs = (threadIdx.x & 3) * 16;
  const float* s = src + (size_t)(r0 + tr) * C + c0 + cs;
  float v[16];
#pragma unroll
  for (int j = 0; j < 16; j += 4) {
    float4v t4 = *(const float4v*)(s + j);
    v[j] = t4.x; v[j + 1] = t4.y; v[j + 2] = t4.z; v[j + 3] = t4.w;
  }
  if (dstN) {
    ushort_t o[16];
#pragma unroll
    for (int j = 0; j < 16; j++) o[j] = f2bf(v[j]);
    ushort_t* d = dstN + (size_t)(r0 + tr) * C + c0 + cs;
    *(short8*)d = *(const short8*)&o[0];
    *(short8*)(d + 8) = *(const short8*)&o[8];
  }
#pragma unroll
  for (int j = 0; j < 16; j++) tile[tr][cs + j] = v[j];
  __syncthreads();
  const int tc = threadIdx.x >> 2, rs = (threadIdx.x & 3) * 16;
  ushort_t o[16];
#pragma unroll
  for (int j = 0; j < 16; j++) o[j] = f2bf(tile[rs + j][tc]);
  ushort_t* d = dstT + (size_t)(c0 + tc) * R + r0 + rs;
  *(short8*)d = *(const short8*)&o[0];
  *(short8*)(d + 8) = *(const short8*)&o[8];
}

// int32 h[R=N][C=E] -> bf16 (x>0) hT SUBTILED + per-block column partial sums.
__global__ __launch_bounds__(256) void tcast_i32_k(
    const int* __restrict__ src, ushort_t* __restrict__ dstT,
    float* __restrict__ partial, int R, int C) {
  __shared__ float tile[64][65];
  const int c0 = blockIdx.x * 64, r0 = blockIdx.y * 64;
  const int tr = threadIdx.x >> 2, cs = (threadIdx.x & 3) * 16;
  const int* s = src + (size_t)(r0 + tr) * C + c0 + cs;
#pragma unroll
  for (int j = 0; j < 16; j += 4) {
    int4v t4 = *(const int4v*)(s + j);
    tile[tr][cs + j] = t4.x > 0 ? 1.f : 0.f;
    tile[tr][cs + j + 1] = t4.y > 0 ? 1.f : 0.f;
    tile[tr][cs + j + 2] = t4.z > 0 ? 1.f : 0.f;
    tile[tr][cs + j + 3] = t4.w > 0 ? 1.f : 0.f;
  }
  __syncthreads();
  const int tc = threadIdx.x >> 2, rs = (threadIdx.x & 3) * 16;
  ushort_t o[16];
#pragma unroll
  for (int j = 0; j < 16; j++) o[j] = f2bf(tile[rs + j][tc]);
  ushort_t* d = dstT + (((size_t)(c0 >> 6) * (size_t)(R >> 6) + (r0 >> 6)) << 12) +
                tc * 64 + rs;
  *(short8*)d = *(const short8*)&o[0];
  *(short8*)(d + 8) = *(const short8*)&o[8];
  if (threadIdx.x < 64) {
    float sum = 0.f;
#pragma unroll
    for (int r = 0; r < 64; r++) sum += tile[r][threadIdx.x];
    partial[(size_t)(r0 >> 6) * C + c0 + threadIdx.x] = sum;
  }
}

// out_bf16[i] = bf16( sum_s P[s][i] ), NSLICE slices
__global__ __launch_bounds__(256) void cast_k(
    const float* __restrict__ P, ushort_t* __restrict__ out, int MN) {
  const int i = (blockIdx.x * 256 + threadIdx.x) * 8;
  float4v a = {0.f, 0.f, 0.f, 0.f}, b = {0.f, 0.f, 0.f, 0.f};
  for (int sp = 0; sp < NSLICE; sp++) {
    a += *(const float4v*)&P[(size_t)sp * MN + i];
    b += *(const float4v*)&P[(size_t)sp * MN + i + 4];
  }
  ushort_t o[8];
  o[0] = f2bf(a.x); o[1] = f2bf(a.y); o[2] = f2bf(a.z); o[3] = f2bf(a.w);
  o[4] = f2bf(b.x); o[5] = f2bf(b.y); o[6] = f2bf(b.z); o[7] = f2bf(b.w);
  *(short8*)&out[i] = *(const short8*)o;
}

// P[s][d][m]: sum NSLICE slices, LayerNorm over d per column m, write xT bf16.
__global__ __launch_bounds__(256) void ln_cast_k(
    const float* __restrict__ P, const float* __restrict__ gamma,
    const float* __restrict__ beta, ushort_t* __restrict__ xT, int Ncols) {
  __shared__ float ssum[8][32], ssq[8][32];
  const int c = threadIdx.x & 31;
  const int q = threadIdx.x >> 5;
  const int m = blockIdx.x * 32 + c;
  const size_t DN = (size_t)128 * Ncols;
  float vloc[16];
  float s = 0.f, sq = 0.f;
#pragma unroll
  for (int j = 0; j < 16; j++) {
    const int d = q * 16 + j;
    float v = 0.f;
    for (int sp = 0; sp < NSLICE; sp++)
      v += P[(size_t)sp * DN + (size_t)d * Ncols + m];
    vloc[j] = v; s += v; sq += v * v;
  }
  ssum[q][c] = s;
  ssq[q][c] = sq;
  __syncthreads();
  float S = 0.f, SQ = 0.f;
#pragma unroll
  for (int r = 0; r < 8; r++) { S += ssum[r][c]; SQ += ssq[r][c]; }
  const float mean = S * (1.f / 128.f);
  const float var = SQ * (1.f / 128.f) - mean * mean;
  const float inv = rsqrtf(var + 1e-5f);
#pragma unroll
  for (int j = 0; j < 16; j++) {
    const int d = q * 16 + j;
    xT[(size_t)d * Ncols + m] = f2bf((vloc[j] - mean) * inv * gamma[d] + beta[d]);
  }
}

// P[s][e][128]: sum NSLICE slices, divide by counts[e] (computed in-block
// from partial), partial max over 16 e/block.
__global__ __launch_bounds__(256) void mm1_k(
    const float* __restrict__ P, const float* __restrict__ partial,
    float* __restrict__ pm, int EMN, int E) {
  __shared__ float scnt[16][9];
  __shared__ float4v red[8][32];
  const int t = threadIdx.x;
  const int e0 = blockIdx.x * 16;
  if (t < 128) {
    const int ee = t >> 3, pp = t & 7;
    float s = 0.f;
#pragma unroll
    for (int r = 0; r < 16; r++)
      s += partial[(size_t)(pp * 16 + r) * E + e0 + ee];
    scnt[ee][pp] = s;
  }
  __syncthreads();
  const int el = t >> 5;
  const int l32 = t & 31;
  float4v vmax = {-3.4e38f, -3.4e38f, -3.4e38f, -3.4e38f};
  for (int ee = el; ee < 16; ee += 8) {
    const int e = e0 + ee;
    float4v s = {0.f, 0.f, 0.f, 0.f};
    for (int sp = 0; sp < NSLICE; sp++)
      s += *(const float4v*)&P[(size_t)sp * EMN + (size_t)e * 128 + l32 * 4];
    float cnt = 0.f;
#pragma unroll
    for (int p = 0; p < 8; p++) cnt += scnt[ee][p];
    const float inv = 1.f / cnt;
    s *= inv;
    vmax.x = fmaxf(vmax.x, s.x); vmax.y = fmaxf(vmax.y, s.y);
    vmax.z = fmaxf(vmax.z, s.z); vmax.w = fmaxf(vmax.w, s.w);
  }
  red[el][l32] = vmax;
  __syncthreads();
  if (el == 0) {
    float4v m = red[0][l32];
#pragma unroll
    for (int r = 1; r < 8; r++) {
      float4v t4 = red[r][l32];
      m.x = fmaxf(m.x, t4.x); m.y = fmaxf(m.y, t4.y);
      m.z = fmaxf(m.z, t4.z); m.w = fmaxf(m.w, t4.w);
    }
    *(float4v*)&pm[(size_t)blockIdx.x * 128 + l32 * 4] = m;
  }
}

__global__ __launch_bounds__(128) void mm2_k(
    const float* __restrict__ pm, float* __restrict__ out, int B) {
  const int d = threadIdx.x;
  float v = -3.4e38f;
  for (int b = 0; b < B; b++) v = fmaxf(v, pm[b * 128 + d]);
  out[d] = v;
}

// ---------------------------------------------------------------------------
extern "C" void kernel_launch(void* const* d_in, const int* in_sizes, int n_in,
                              void* d_out, int out_size, void* d_ws,
                              size_t ws_size, hipStream_t stream) {
  const float* x0 = (const float*)d_in[0];
  const float* T = (const float*)d_in[1];
  const float* gamma = (const float*)d_in[2];
  const float* beta = (const float*)d_in[3];
  const int* h = (const int*)d_in[4];
  float* out = (float*)d_out;

  const int N = 8192, E = 4096, D = 128, K = 8192, S = NSLICE;

  char* ws = (char*)d_ws;
  size_t off = 0;
  auto alloc = [&](size_t bytes) {
    char* p = ws + off;
    off += (bytes + 255) & ~(size_t)255;
    return p;
  };
  ushort_t* Tb = (ushort_t*)alloc((size_t)N * N * 2);  // T bf16 SUBTILED
  ushort_t* hT = (ushort_t*)alloc((size_t)E * N * 2);  // h^T bf16 SUBTILED
  ushort_t* xT = (ushort_t*)alloc((size_t)D * N * 2);  // x^T bf16 [128][8192]
  ushort_t* tT = (ushort_t*)alloc((size_t)D * N * 2);  // t^T bf16 [128][8192]
  float* P = (float*)alloc((size_t)S * D * N * 4);     // split-K partials 64MB
  float* partial = (float*)alloc((size_t)(N / 64) * E * 4);  // 2MB count partials
  float* pm = (float*)alloc((size_t)256 * D * 4);
  (void)ws_size;

  repack_T_k<<<dim3(16, 256), 256, 0, stream>>>(T, Tb);
  dualcast_f32_k<<<dim3(D / 64, N / 64), 256, 0, stream>>>(x0, nullptr, xT, N, D);
  tcast_i32_k<<<dim3(E / 64, N / 64), 256, 0, stream>>>(h, hT, partial, N, E);

  for (int layer = 0; layer < 3; layer++) {
    // tT[d][n] = sum_k xT[d][k] * T[n][k]  (TN; B = Tb tiled)
    gemm_tn<<<dim3(1, N / 128, S), 256, 0, stream>>>(xT, Tb, P, D, N, K, 0, 1);
    cast_k<<<D * N / (256 * 8), 256, 0, stream>>>(P, tT, D * N);
    // x'T[d][m] = sum_k tT[d][k] * T[k][m]  (NN; B = Tb tiled)
    gemm_nn<<<dim3(1, N / 128, S), 256, 0, stream>>>(tT, Tb, P, D, N, K);
    ln_cast_k<<<N / 32, 256, 0, stream>>>(P, gamma, beta, xT, N);
  }
  // sums[e][d] = sum_n hT[e][n] * xT[d][n]  (TN; A = hT tiled, B = xT rowmajor)
  gemm_tn<<<dim3(E / 128, 1, S), 256, 0, stream>>>(hT, xT, P, E, D, K, 1, 0);
  mm1_k<<<E / 16, 256, 0, stream>>>(P, partial, pm, E * D, E);
  mm2_k<<<1, 128, 0, stream>>>(pm, out, E / 16);
}